// Round 5
// baseline (1880.613 us; speedup 1.0000x reference)
//
#include <hip/hip_runtime.h>
#include <stdint.h>

#define TT  1024
#define BB  512
#define OBS 128
#define HH  64
#define AA  18
#define RT  (TT*BB)                         // 524288 rows
#define OFF_L ((size_t)BB*HH)
#define OFF_V (OFF_L + (size_t)TT*BB*AA)

#define GI_ELEMS ((size_t)RT*192)           // 100,663,296 floats
#define WS_NEED  ((GI_ELEMS + (size_t)RT*HH)*4)   // 512 MiB exactly

__device__ __forceinline__ float fast_rcp(float x){ return __builtin_amdgcn_rcpf(x); }
__device__ __forceinline__ float sigm(float x){ return fast_rcp(1.f + __expf(-x)); }
__device__ __forceinline__ float tanh_(float x){ return 1.f - 2.f*fast_rcp(1.f + __expf(2.f*x)); }
__device__ __forceinline__ float bcast(float v, int k){
    return __int_as_float(__builtin_amdgcn_readlane(__float_as_int(v), k));
}

// ---- mask-dtype detection: any uint32 word >1 => byte-packed bool ----
__global__ void detect_mask(const uint32_t* __restrict__ m, uint32_t* __restrict__ flag)
{
    const int n_words = (TT * BB) / 4;
    uint32_t acc = 0;
    for (int i = blockIdx.x * blockDim.x + threadIdx.x; i < n_words;
         i += gridDim.x * blockDim.x)
        acc |= (m[i] > 1u) ? 1u : 0u;
    if (acc) flag[0] = 1u;
}

// ================= pass 1: gi = relu(x@W1+b1)@Wi+bi  ====================
#define P1_BLOCKS 1024
#define P1_RPB (RT/P1_BLOCKS)   // 512 rows per block
#define RPI 8
#define P1_ITERS (P1_RPB/RPI)   // 64

__global__ __launch_bounds__(256, 2)
void stem_gi(const float* __restrict__ x,
             const float* __restrict__ W1, const float* __restrict__ b1,
             const float* __restrict__ Wi, const float* __restrict__ bi,
             float* __restrict__ gi)
{
    const int tid = threadIdx.x, w = tid >> 6, lane = tid & 63;
    const int js = (w << 4) | (lane >> 2), kc = lane & 3;
    __shared__ float4 x_l4[2][RPI][32];   // 2 x 4KB row chunks
    __shared__ float4 z_l4[RPI][16];

    float w1r[32];
    #pragma unroll
    for (int i = 0; i < 32; ++i) w1r[i] = W1[(kc*32 + i)*HH + js];
    const float b1v = b1[js];
    float wA[64]; float biv = 0.f;
    if (tid < 192) {
        #pragma unroll
        for (int k = 0; k < 64; ++k) wA[k] = Wi[k*192 + tid];
        biv = bi[tid];
    }
    const size_t row0 = (size_t)blockIdx.x * P1_RPB;

    {
        const float* gsrc = &x[row0*OBS] + tid*4;
        void* ldst = (char*)&x_l4[0][0][0] + w*1024;
        __builtin_amdgcn_global_load_lds(
            (const __attribute__((address_space(1))) void*)gsrc,
            (__attribute__((address_space(3))) void*)ldst, 16, 0, 0);
    }
    __syncthreads();

    for (int it = 0; it < P1_ITERS; ++it) {
        const int p = it & 1;
        // ---- phase A: stem for RPI rows ----
        #pragma unroll
        for (int r = 0; r < RPI; ++r) {
            const float4* xr = &x_l4[p][r][kc*8];
            float acc = 0.f;
            #pragma unroll
            for (int q = 0; q < 8; ++q) {
                const float4 xv = xr[q];
                acc += w1r[4*q+0]*xv.x + w1r[4*q+1]*xv.y
                     + w1r[4*q+2]*xv.z + w1r[4*q+3]*xv.w;
            }
            acc += __shfl_xor(acc, 1);
            acc += __shfl_xor(acc, 2);
            if (kc == 0) ((float*)&z_l4[r][0])[js] = fmaxf(acc + b1v, 0.f);
        }
        __syncthreads();   // z_l4 ready
        if (it + 1 < P1_ITERS) {
            const float* gsrc = &x[(row0 + (size_t)(it+1)*RPI)*OBS] + tid*4;
            void* ldst = (char*)&x_l4[p^1][0][0] + w*1024;
            __builtin_amdgcn_global_load_lds(
                (const __attribute__((address_space(1))) void*)gsrc,
                (__attribute__((address_space(3))) void*)ldst, 16, 0, 0);
        }
        // ---- phase B: gi for RPI rows ----
        if (tid < 192) {
            #pragma unroll
            for (int r = 0; r < RPI; ++r) {
                const float4* zr = &z_l4[r][0];
                float acc = biv;
                #pragma unroll
                for (int kk = 0; kk < 16; ++kk) {
                    const float4 zv = zr[kk];
                    acc += wA[4*kk+0]*zv.x + wA[4*kk+1]*zv.y
                         + wA[4*kk+2]*zv.z + wA[4*kk+3]*zv.w;
                }
                gi[(row0 + (size_t)it*RPI + r)*192 + tid] = acc;
            }
        }
        __syncthreads();
    }
}

// ===== pass 2: serial GRU — 3 waves/chain, gate-split, readlane bcast ====
// Forced textual unroll => wg[] register-promoted, readlane gets literals.
__global__ __launch_bounds__(192, 1)
void recur3(const float* __restrict__ gi,
            const void* __restrict__ mask_raw,
            const uint32_t* __restrict__ mflag,
            const float* __restrict__ ic,
            const float* __restrict__ Wh,
            const float* __restrict__ bhn,
            float* __restrict__ ys,
            float* __restrict__ out)
{
    const int b = blockIdx.x, tid = threadIdx.x;
    const int g = tid >> 6, j = tid & 63;

    // SoA gate exchange (4B stride -> conflict-free), parity double-buffered
    __shared__ float s_r[2][64], s_u[2][64], s_nacc[2][64], s_gin[2][64];
    __shared__ uint8_t m_l[TT];

    if (mflag[0] != 0) {
        const uint8_t* m8 = (const uint8_t*)mask_raw;
        for (int t = tid; t < TT; t += 192) m_l[t] = m8[(size_t)t*BB + b];
    } else {
        const int32_t* m32 = (const int32_t*)mask_raw;
        for (int t = tid; t < TT; t += 192) m_l[t] = (uint8_t)(m32[(size_t)t*BB + b] != 0);
    }

    // per-wave weights: wave g holds Wh[:, 64g + j]
    float wg[64];
    #pragma unroll
    for (int k = 0; k < 64; ++k) wg[k] = Wh[k*192 + (g<<6) + j];
    const float icj  = ic[b*HH + j];
    const float bhnj = bhn[j];

    __syncthreads();  // m_l staged

    float hj = icj;
    const float* gcol = gi + (size_t)b*192 + (g<<6) + j;   // stride BB*192 per t
    float gp0 = gcol[0];
    float gp1 = gcol[(size_t)BB*192];
    int mc = m_l[0], mn = m_l[1];

    for (int t = 0; t < TT; ++t) {
        const int p = t & 1;
        const float heff = mc ? icj : hj;

        // prefetch t+2 (covers ~2 steps of HBM latency)
        float gp2 = 0.f; int m2 = 0;
        if (t + 2 < TT) {
            gp2 = gcol[(size_t)(t+2)*BB*192];
            m2  = m_l[t+2];
        }

        // gate dot: 4 partial accumulators, textually unrolled
        float a0 = (g == 2) ? bhnj : gp0;   // seed: gi for r/z gates, bhn for n
        float a1 = 0.f, a2 = 0.f, a3 = 0.f;
#define K4(k) { a0 = fmaf(bcast(heff,(k)+0), wg[(k)+0], a0); \
                a1 = fmaf(bcast(heff,(k)+1), wg[(k)+1], a1); \
                a2 = fmaf(bcast(heff,(k)+2), wg[(k)+2], a2); \
                a3 = fmaf(bcast(heff,(k)+3), wg[(k)+3], a3); }
        K4(0)  K4(4)  K4(8)  K4(12) K4(16) K4(20) K4(24) K4(28)
        K4(32) K4(36) K4(40) K4(44) K4(48) K4(52) K4(56) K4(60)
#undef K4
        const float acc = (a0 + a1) + (a2 + a3);

        if (g == 0)      s_r[p][j] = sigm(acc);
        else if (g == 1) s_u[p][j] = sigm(acc);
        else {           s_nacc[p][j] = acc;     // ghn + bhn
                         s_gin[p][j]  = gp0; }   // gin
        __syncthreads();   // gate values(t) published

        const float rv   = s_r[p][j];
        const float uv   = s_u[p][j];
        const float nac  = s_nacc[p][j];
        const float ginv = s_gin[p][j];
        const float nv = tanh_(fmaf(rv, nac, ginv));
        hj = uv * (heff - nv) + nv;

        if (g == 0) ys[((size_t)t*BB + b)*HH + j] = hj;

        gp0 = gp1; gp1 = gp2; mc = mn; mn = m2;
    }
    if (g == 0) out[(size_t)b*HH + j] = hj;   // h_final
}

// ================= pass 3: heads, wave-local, no barriers ===============
#define P3_BLOCKS 1024
#define P3_RPW (RT/(P3_BLOCKS*4))   // 128 rows per wave

__global__ __launch_bounds__(256, 2)
void heads(const float* __restrict__ ys,
           const float* __restrict__ W2, const float* __restrict__ b2,
           const float* __restrict__ Wl, const float* __restrict__ bl,
           const float* __restrict__ Wv, const float* __restrict__ bv,
           float* __restrict__ out)
{
    const int tid = threadIdx.x, w = tid >> 6, lane = tid & 63;
    __shared__ float4 sb[4][2][16];
    float w2r[64];
    #pragma unroll
    for (int k = 0; k < 64; ++k) w2r[k] = W2[k*HH + lane];
    const float b2v = b2[lane];
    float wc[64]; float bcv = 0.f;
    if (lane < AA) {
        #pragma unroll
        for (int k = 0; k < 64; ++k) wc[k] = Wl[k*AA + lane];
        bcv = bl[lane];
    } else if (lane == AA) {
        #pragma unroll
        for (int k = 0; k < 64; ++k) wc[k] = Wv[k];
        bcv = bv[0];
    } else {
        #pragma unroll
        for (int k = 0; k < 64; ++k) wc[k] = 0.f;
    }
    const int r0 = (blockIdx.x*4 + w) * P3_RPW;
    float ysA = ys[(size_t)r0*HH + lane];
    float ysB = ys[(size_t)(r0+1)*HH + lane];
    for (int rr = 0; rr < P3_RPW; ++rr) {
        const int row = r0 + rr;
        const float ysv = ysA;
        ysA = ysB;
        const int rn = (rr+2 < P3_RPW) ? (row+2) : (r0 + P3_RPW - 1);
        ysB = ys[(size_t)rn*HH + lane];
        ((float*)&sb[w][0][0])[lane] = ysv;
        float acc = b2v;
        {
            const float4* yb = &sb[w][0][0];
            #pragma unroll
            for (int kk = 0; kk < 16; ++kk) {
                const float4 v = yb[kk];
                acc += w2r[4*kk+0]*v.x + w2r[4*kk+1]*v.y
                     + w2r[4*kk+2]*v.z + w2r[4*kk+3]*v.w;
            }
        }
        const float yv = fmaxf(acc, 0.f);
        ((float*)&sb[w][1][0])[lane] = yv;
        float acc2 = bcv;
        {
            const float4* yb = &sb[w][1][0];
            #pragma unroll
            for (int kk = 0; kk < 16; ++kk) {
                const float4 v = yb[kk];
                acc2 += wc[4*kk+0]*v.x + wc[4*kk+1]*v.y
                      + wc[4*kk+2]*v.z + wc[4*kk+3]*v.w;
            }
        }
        if (lane < AA)       out[OFF_L + (size_t)row*AA + lane] = acc2;
        else if (lane == AA) out[OFF_V + row] = acc2;
    }
}

// ================= fallback: round-2 fused kernel (known-correct) =======
__global__ __launch_bounds__(256, 2)
void gru_agent(const float* __restrict__ x,
               const void* __restrict__ mask_raw,
               const uint32_t* __restrict__ mask_flag,
               const float* __restrict__ ic,
               const float* __restrict__ W1, const float* __restrict__ b1,
               const float* __restrict__ Wi, const float* __restrict__ bi,
               const float* __restrict__ Wh, const float* __restrict__ bhn,
               const float* __restrict__ W2, const float* __restrict__ b2,
               const float* __restrict__ Wl, const float* __restrict__ bl,
               const float* __restrict__ Wv, const float* __restrict__ bv,
               float* __restrict__ out)
{
    const int b    = blockIdx.x;
    const int tid  = threadIdx.x;
    const int w    = tid >> 6;
    const int lane = tid & 63;

    const bool mask_is_u8 = (mask_flag[0] != 0);
    const uint8_t* __restrict__ m8  = (const uint8_t*)mask_raw;
    const int32_t* __restrict__ m32 = (const int32_t*)mask_raw;

    __shared__ float4 x_l[2][4][9];
    __shared__ float4 z_l[16];
    __shared__ float4 h_l[2][16];
    __shared__ float4 y_l[2][16];
    __shared__ float4 ic_l[16];
    __shared__ float  gi_l[192];
    __shared__ float  gh_l[192];

    const int js = (w << 4) | (lane >> 2);
    const int kc = lane & 3;
    float w1r[32];
    #pragma unroll
    for (int i = 0; i < 32; ++i) w1r[i] = W1[(kc*32 + i)*HH + js];
    const float b1v = b1[js];

    float wA[64], wB[64];
    float biv = 0.f, b2v = 0.f, blv = 0.f;
    if (w < 3) {
        const int n = tid;
        #pragma unroll
        for (int k = 0; k < 64; ++k) wA[k] = Wi[k*(3*HH) + n];
        #pragma unroll
        for (int k = 0; k < 64; ++k) wB[k] = Wh[k*(3*HH) + n];
        biv = bi[n];
    } else {
        #pragma unroll
        for (int k = 0; k < 64; ++k) wA[k] = W2[k*HH + lane];
        #pragma unroll
        for (int k = 0; k < 64; ++k) wB[k] = (lane < AA) ? Wl[k*AA + lane]
                                           : (lane == AA ? Wv[k] : 0.f);
        b2v = b2[lane];
        blv = (lane < AA) ? bl[lane] : (lane == AA ? bv[0] : 0.f);
    }
    const float bhnv = (tid < HH) ? bhn[tid] : 0.f;

    if (tid < HH) {
        float v = ic[b*HH + tid];
        ((float*)ic_l)[tid]   = v;
        ((float*)h_l[0])[tid] = v;
    }
    if (tid < OBS) {
        float xv = x[(0*BB + b)*OBS + tid];
        ((float*)&x_l[0][tid>>5])[tid&31] = xv;
    }
    uint8_t m_cur = mask_is_u8 ? m8[b] : (uint8_t)(m32[b] != 0);
    __syncthreads();

    for (int t = 0; t < TT + 2; ++t) {
        const int p = t & 1;
        float xnext = 0.f;
        if (t + 1 < TT && tid < OBS) xnext = x[((t+1)*BB + b)*OBS + tid];
        uint8_t m_next = 0;
        if (t + 1 < TT) {
            const int mi = (t+1)*BB + b;
            m_next = mask_is_u8 ? m8[mi] : (uint8_t)(m32[mi] != 0);
        }
        if (t < TT) {
            const float4* xr = &x_l[p][kc][0];
            float acc = 0.f;
            #pragma unroll
            for (int q = 0; q < 8; ++q) {
                float4 xv = xr[q];
                acc += w1r[4*q+0]*xv.x + w1r[4*q+1]*xv.y
                     + w1r[4*q+2]*xv.z + w1r[4*q+3]*xv.w;
            }
            acc += __shfl_xor(acc, 1);
            acc += __shfl_xor(acc, 2);
            if (kc == 0) ((float*)z_l)[js] = fmaxf(acc + b1v, 0.f);
        }
        if (t < TT && w < 3) {
            const float4* hs = m_cur ? ic_l : h_l[p];
            float acc = 0.f;
            #pragma unroll
            for (int kk = 0; kk < 16; ++kk) {
                float4 hv = hs[kk];
                acc += wB[4*kk+0]*hv.x + wB[4*kk+1]*hv.y
                     + wB[4*kk+2]*hv.z + wB[4*kk+3]*hv.w;
            }
            gh_l[tid] = acc;
        } else if (w == 3 && t >= 1 && t <= TT) {
            const float4* hs = h_l[p];
            float acc = b2v;
            #pragma unroll
            for (int kk = 0; kk < 16; ++kk) {
                float4 hv = hs[kk];
                acc += wA[4*kk+0]*hv.x + wA[4*kk+1]*hv.y
                     + wA[4*kk+2]*hv.z + wA[4*kk+3]*hv.w;
            }
            ((float*)y_l[p])[lane] = fmaxf(acc, 0.f);
        }
        __syncthreads();
        if (t < TT && w < 3) {
            float acc = biv;
            #pragma unroll
            for (int kk = 0; kk < 16; ++kk) {
                float4 zv = z_l[kk];
                acc += wA[4*kk+0]*zv.x + wA[4*kk+1]*zv.y
                     + wA[4*kk+2]*zv.z + wA[4*kk+3]*zv.w;
            }
            gi_l[tid] = acc;
        } else if (w == 3 && t >= 2) {
            const float4* yss = y_l[p ^ 1];
            float acc = blv;
            #pragma unroll
            for (int kk = 0; kk < 16; ++kk) {
                float4 yv = yss[kk];
                acc += wB[4*kk+0]*yv.x + wB[4*kk+1]*yv.y
                     + wB[4*kk+2]*yv.z + wB[4*kk+3]*yv.w;
            }
            if (lane < AA)       out[OFF_L + (size_t)((t-2)*BB + b)*AA + lane] = acc;
            else if (lane == AA) out[OFF_V + (size_t)(t-2)*BB + b] = acc;
        }
        __syncthreads();
        if (t < TT && tid < HH) {
            const int j = tid;
            const float irv = gi_l[j], izv = gi_l[HH+j], inn = gi_l[2*HH+j];
            const float hrv = gh_l[j], hzv = gh_l[HH+j], hnv = gh_l[2*HH+j];
            const float heff = m_cur ? ((const float*)ic_l)[j]
                                     : ((const float*)h_l[p])[j];
            const float r  = sigm(irv + hrv);
            const float u  = sigm(izv + hzv);
            const float nn = tanh_(inn + r*(hnv + bhnv));
            ((float*)h_l[p ^ 1])[j] = u*(heff - nn) + nn;
        }
        if (t + 1 < TT && tid < OBS) {
            ((float*)&x_l[p ^ 1][tid>>5])[tid&31] = xnext;
        }
        m_cur = m_next;
        __syncthreads();
    }
    if (tid < HH) out[(size_t)b*HH + tid] = ((const float*)h_l[TT & 1])[tid];
}

extern "C" void kernel_launch(void* const* d_in, const int* in_sizes, int n_in,
                              void* d_out, int out_size, void* d_ws, size_t ws_size,
                              hipStream_t stream) {
    const float* x    = (const float*)d_in[0];
    const void*  mask = (const void*) d_in[1];
    const float* ic   = (const float*)d_in[2];
    const float* W1   = (const float*)d_in[3];
    const float* b1   = (const float*)d_in[4];
    const float* Wi   = (const float*)d_in[5];
    const float* bi   = (const float*)d_in[6];
    const float* Wh   = (const float*)d_in[7];
    const float* bhn  = (const float*)d_in[8];
    const float* W2   = (const float*)d_in[9];
    const float* b2   = (const float*)d_in[10];
    const float* Wl   = (const float*)d_in[11];
    const float* bl   = (const float*)d_in[12];
    const float* Wv   = (const float*)d_in[13];
    const float* bv   = (const float*)d_in[14];
    float* out = (float*)d_out;

    if (ws_size >= WS_NEED) {
        float* gi = (float*)d_ws;
        float* ys = gi + GI_ELEMS;
        uint32_t* flag = (uint32_t*)(out + OFF_V + RT - 1);
        hipMemsetAsync(flag, 0, sizeof(uint32_t), stream);
        detect_mask<<<64, 256, 0, stream>>>((const uint32_t*)mask, flag);
        stem_gi<<<P1_BLOCKS, 256, 0, stream>>>(x, W1, b1, Wi, bi, gi);
        recur3<<<BB, 192, 0, stream>>>(gi, mask, flag, ic, Wh, bhn, ys, out);
        heads<<<P3_BLOCKS, 256, 0, stream>>>(ys, W2, b2, Wl, bl, Wv, bv, out);
    } else {
        uint32_t* flag = (uint32_t*)d_ws;
        hipMemsetAsync(flag, 0, sizeof(uint32_t), stream);
        detect_mask<<<64, 256, 0, stream>>>((const uint32_t*)mask, flag);
        gru_agent<<<BB, 256, 0, stream>>>(x, mask, flag, ic, W1, b1, Wi, bi, Wh, bhn,
                                          W2, b2, Wl, bl, Wv, bv, out);
    }
}

// Round 6
// 1607.058 us; speedup vs baseline: 1.1702x; 1.1702x over previous
//
#include <hip/hip_runtime.h>
#include <stdint.h>

#define TT  1024
#define BB  512
#define OBS 128
#define HH  64
#define AA  18
#define RT  (TT*BB)                         // 524288 rows
#define OFF_L ((size_t)BB*HH)
#define OFF_V (OFF_L + (size_t)TT*BB*AA)

#define GI_ELEMS ((size_t)RT*192)           // 100,663,296 floats
#define WS_NEED  ((GI_ELEMS + (size_t)RT*HH)*4)   // 512 MiB exactly

__device__ __forceinline__ float fast_rcp(float x){ return __builtin_amdgcn_rcpf(x); }
__device__ __forceinline__ float sigm(float x){ return fast_rcp(1.f + __expf(-x)); }
__device__ __forceinline__ float tanh_(float x){ return 1.f - 2.f*fast_rcp(1.f + __expf(2.f*x)); }
__device__ __forceinline__ float bcast(float v, int k){
    return __int_as_float(__builtin_amdgcn_readlane(__float_as_int(v), k));
}

// ---- mask-dtype detection: any uint32 word >1 => byte-packed bool ----
__global__ void detect_mask(const uint32_t* __restrict__ m, uint32_t* __restrict__ flag)
{
    const int n_words = (TT * BB) / 4;
    uint32_t acc = 0;
    for (int i = blockIdx.x * blockDim.x + threadIdx.x; i < n_words;
         i += gridDim.x * blockDim.x)
        acc |= (m[i] > 1u) ? 1u : 0u;
    if (acc) flag[0] = 1u;
}

// ================= pass 1: gi = relu(x@W1+b1)@Wi+bi  ====================
#define P1_BLOCKS 1024
#define P1_RPB (RT/P1_BLOCKS)   // 512 rows per block
#define RPI 8
#define P1_ITERS (P1_RPB/RPI)   // 64

__global__ __launch_bounds__(256, 2)
void stem_gi(const float* __restrict__ x,
             const float* __restrict__ W1, const float* __restrict__ b1,
             const float* __restrict__ Wi, const float* __restrict__ bi,
             float* __restrict__ gi)
{
    const int tid = threadIdx.x, w = tid >> 6, lane = tid & 63;
    const int js = (w << 4) | (lane >> 2), kc = lane & 3;
    __shared__ float4 x_l4[2][RPI][32];   // 2 x 4KB row chunks
    __shared__ float4 z_l4[RPI][16];

    float w1r[32];
    #pragma unroll
    for (int i = 0; i < 32; ++i) w1r[i] = W1[(kc*32 + i)*HH + js];
    const float b1v = b1[js];
    float wA[64]; float biv = 0.f;
    if (tid < 192) {
        #pragma unroll
        for (int k = 0; k < 64; ++k) wA[k] = Wi[k*192 + tid];
        biv = bi[tid];
    }
    const size_t row0 = (size_t)blockIdx.x * P1_RPB;

    {
        const float* gsrc = &x[row0*OBS] + tid*4;
        void* ldst = (char*)&x_l4[0][0][0] + w*1024;
        __builtin_amdgcn_global_load_lds(
            (const __attribute__((address_space(1))) void*)gsrc,
            (__attribute__((address_space(3))) void*)ldst, 16, 0, 0);
    }
    __syncthreads();

    for (int it = 0; it < P1_ITERS; ++it) {
        const int p = it & 1;
        // ---- phase A: stem for RPI rows ----
        #pragma unroll
        for (int r = 0; r < RPI; ++r) {
            const float4* xr = &x_l4[p][r][kc*8];
            float acc = 0.f;
            #pragma unroll
            for (int q = 0; q < 8; ++q) {
                const float4 xv = xr[q];
                acc += w1r[4*q+0]*xv.x + w1r[4*q+1]*xv.y
                     + w1r[4*q+2]*xv.z + w1r[4*q+3]*xv.w;
            }
            acc += __shfl_xor(acc, 1);
            acc += __shfl_xor(acc, 2);
            if (kc == 0) ((float*)&z_l4[r][0])[js] = fmaxf(acc + b1v, 0.f);
        }
        __syncthreads();   // z_l4 ready
        if (it + 1 < P1_ITERS) {
            const float* gsrc = &x[(row0 + (size_t)(it+1)*RPI)*OBS] + tid*4;
            void* ldst = (char*)&x_l4[p^1][0][0] + w*1024;
            __builtin_amdgcn_global_load_lds(
                (const __attribute__((address_space(1))) void*)gsrc,
                (__attribute__((address_space(3))) void*)ldst, 16, 0, 0);
        }
        // ---- phase B: gi for RPI rows ----
        if (tid < 192) {
            #pragma unroll
            for (int r = 0; r < RPI; ++r) {
                const float4* zr = &z_l4[r][0];
                float acc = biv;
                #pragma unroll
                for (int kk = 0; kk < 16; ++kk) {
                    const float4 zv = zr[kk];
                    acc += wA[4*kk+0]*zv.x + wA[4*kk+1]*zv.y
                         + wA[4*kk+2]*zv.z + wA[4*kk+3]*zv.w;
                }
                gi[(row0 + (size_t)it*RPI + r)*192 + tid] = acc;
            }
        }
        __syncthreads();
    }
}

// ===== pass 2: serial GRU — 3 waves/chain, gate-split, readlane bcast ====
// wg[] pinned into VGPRs via opaque asm (defeats rematerialization).
__global__ __launch_bounds__(192, 1)
void recur3(const float* __restrict__ gi,
            const void* __restrict__ mask_raw,
            const uint32_t* __restrict__ mflag,
            const float* __restrict__ ic,
            const float* __restrict__ Wh,
            const float* __restrict__ bhn,
            float* __restrict__ ys,
            float* __restrict__ out)
{
    const int b = blockIdx.x, tid = threadIdx.x;
    const int g = tid >> 6, j = tid & 63;

    // SoA gate exchange (4B stride -> conflict-free), parity double-buffered
    __shared__ float s_r[2][64], s_u[2][64], s_nacc[2][64], s_gin[2][64];
    __shared__ uint8_t m_l[TT];

    if (mflag[0] != 0) {
        const uint8_t* m8 = (const uint8_t*)mask_raw;
        for (int t = tid; t < TT; t += 192) m_l[t] = m8[(size_t)t*BB + b];
    } else {
        const int32_t* m32 = (const int32_t*)mask_raw;
        for (int t = tid; t < TT; t += 192) m_l[t] = (uint8_t)(m32[(size_t)t*BB + b] != 0);
    }

    // per-wave weights: wave g holds Wh[:, 64g + j]
    float wg[64];
    #pragma unroll
    for (int k = 0; k < 64; ++k) wg[k] = Wh[k*192 + (g<<6) + j];
    // PIN: force each weight into a live VGPR; opaque asm makes the value
    // unknowable => compiler cannot rematerialize the load inside the t-loop.
    #pragma unroll
    for (int k = 0; k < 64; ++k) asm volatile("" : "+v"(wg[k]));

    const float icj  = ic[b*HH + j];
    const float bhnj = bhn[j];

    __syncthreads();  // m_l staged

    float hj = icj;
    const float* gcol = gi + (size_t)b*192 + (g<<6) + j;   // stride BB*192 per t
    // depth-3 prefetch pipeline
    float g0 = gcol[0];
    float g1 = gcol[(size_t)1*BB*192];
    float g2 = gcol[(size_t)2*BB*192];
    int m0 = m_l[0], m1 = m_l[1], m2 = m_l[2];

    for (int t = 0; t < TT; ++t) {
        const int p = t & 1;
        const float heff = m0 ? icj : hj;

        // prefetch t+3 (clamped; gi/m_l fully valid)
        const int tp = (t + 3 < TT) ? (t + 3) : (TT - 1);
        const float g3 = gcol[(size_t)tp*BB*192];
        const int   m3 = m_l[tp];

        // gate dot: 4 partial accumulators, textually unrolled
        float a0 = (g == 2) ? bhnj : g0;    // seed: gi for r/z gates, bhn for n
        float a1 = 0.f, a2 = 0.f, a3 = 0.f;
#define K4(k) { a0 = fmaf(bcast(heff,(k)+0), wg[(k)+0], a0); \
                a1 = fmaf(bcast(heff,(k)+1), wg[(k)+1], a1); \
                a2 = fmaf(bcast(heff,(k)+2), wg[(k)+2], a2); \
                a3 = fmaf(bcast(heff,(k)+3), wg[(k)+3], a3); }
        K4(0)  K4(4)  K4(8)  K4(12) K4(16) K4(20) K4(24) K4(28)
        K4(32) K4(36) K4(40) K4(44) K4(48) K4(52) K4(56) K4(60)
#undef K4
        const float acc = (a0 + a1) + (a2 + a3);

        if (g == 0)      s_r[p][j] = sigm(acc);
        else if (g == 1) s_u[p][j] = sigm(acc);
        else {           s_nacc[p][j] = acc;     // ghn + bhn
                         s_gin[p][j]  = g0; }    // gin
        __syncthreads();   // gate values(t) published

        const float rv   = s_r[p][j];
        const float uv   = s_u[p][j];
        const float nac  = s_nacc[p][j];
        const float ginv = s_gin[p][j];
        const float nv = tanh_(fmaf(rv, nac, ginv));
        hj = uv * (heff - nv) + nv;

        if (g == 0) ys[((size_t)t*BB + b)*HH + j] = hj;

        g0 = g1; g1 = g2; g2 = g3;
        m0 = m1; m1 = m2; m2 = m3;
    }
    if (g == 0) out[(size_t)b*HH + j] = hj;   // h_final
}

// ================= pass 3: heads, wave-local, no barriers ===============
#define P3_BLOCKS 1024
#define P3_RPW (RT/(P3_BLOCKS*4))   // 128 rows per wave

__global__ __launch_bounds__(256, 2)
void heads(const float* __restrict__ ys,
           const float* __restrict__ W2, const float* __restrict__ b2,
           const float* __restrict__ Wl, const float* __restrict__ bl,
           const float* __restrict__ Wv, const float* __restrict__ bv,
           float* __restrict__ out)
{
    const int tid = threadIdx.x, w = tid >> 6, lane = tid & 63;
    __shared__ float4 sb[4][2][16];
    float w2r[64];
    #pragma unroll
    for (int k = 0; k < 64; ++k) w2r[k] = W2[k*HH + lane];
    const float b2v = b2[lane];
    float wc[64]; float bcv = 0.f;
    if (lane < AA) {
        #pragma unroll
        for (int k = 0; k < 64; ++k) wc[k] = Wl[k*AA + lane];
        bcv = bl[lane];
    } else if (lane == AA) {
        #pragma unroll
        for (int k = 0; k < 64; ++k) wc[k] = Wv[k];
        bcv = bv[0];
    } else {
        #pragma unroll
        for (int k = 0; k < 64; ++k) wc[k] = 0.f;
    }
    const int r0 = (blockIdx.x*4 + w) * P3_RPW;
    float ysA = ys[(size_t)r0*HH + lane];
    float ysB = ys[(size_t)(r0+1)*HH + lane];
    for (int rr = 0; rr < P3_RPW; ++rr) {
        const int row = r0 + rr;
        const float ysv = ysA;
        ysA = ysB;
        const int rn = (rr+2 < P3_RPW) ? (row+2) : (r0 + P3_RPW - 1);
        ysB = ys[(size_t)rn*HH + lane];
        ((float*)&sb[w][0][0])[lane] = ysv;
        float acc = b2v;
        {
            const float4* yb = &sb[w][0][0];
            #pragma unroll
            for (int kk = 0; kk < 16; ++kk) {
                const float4 v = yb[kk];
                acc += w2r[4*kk+0]*v.x + w2r[4*kk+1]*v.y
                     + w2r[4*kk+2]*v.z + w2r[4*kk+3]*v.w;
            }
        }
        const float yv = fmaxf(acc, 0.f);
        ((float*)&sb[w][1][0])[lane] = yv;
        float acc2 = bcv;
        {
            const float4* yb = &sb[w][1][0];
            #pragma unroll
            for (int kk = 0; kk < 16; ++kk) {
                const float4 v = yb[kk];
                acc2 += wc[4*kk+0]*v.x + wc[4*kk+1]*v.y
                      + wc[4*kk+2]*v.z + wc[4*kk+3]*v.w;
            }
        }
        if (lane < AA)       out[OFF_L + (size_t)row*AA + lane] = acc2;
        else if (lane == AA) out[OFF_V + row] = acc2;
    }
}

// ================= fallback: round-2 fused kernel (known-correct) =======
__global__ __launch_bounds__(256, 2)
void gru_agent(const float* __restrict__ x,
               const void* __restrict__ mask_raw,
               const uint32_t* __restrict__ mask_flag,
               const float* __restrict__ ic,
               const float* __restrict__ W1, const float* __restrict__ b1,
               const float* __restrict__ Wi, const float* __restrict__ bi,
               const float* __restrict__ Wh, const float* __restrict__ bhn,
               const float* __restrict__ W2, const float* __restrict__ b2,
               const float* __restrict__ Wl, const float* __restrict__ bl,
               const float* __restrict__ Wv, const float* __restrict__ bv,
               float* __restrict__ out)
{
    const int b    = blockIdx.x;
    const int tid  = threadIdx.x;
    const int w    = tid >> 6;
    const int lane = tid & 63;

    const bool mask_is_u8 = (mask_flag[0] != 0);
    const uint8_t* __restrict__ m8  = (const uint8_t*)mask_raw;
    const int32_t* __restrict__ m32 = (const int32_t*)mask_raw;

    __shared__ float4 x_l[2][4][9];
    __shared__ float4 z_l[16];
    __shared__ float4 h_l[2][16];
    __shared__ float4 y_l[2][16];
    __shared__ float4 ic_l[16];
    __shared__ float  gi_l[192];
    __shared__ float  gh_l[192];

    const int js = (w << 4) | (lane >> 2);
    const int kc = lane & 3;
    float w1r[32];
    #pragma unroll
    for (int i = 0; i < 32; ++i) w1r[i] = W1[(kc*32 + i)*HH + js];
    const float b1v = b1[js];

    float wA[64], wB[64];
    float biv = 0.f, b2v = 0.f, blv = 0.f;
    if (w < 3) {
        const int n = tid;
        #pragma unroll
        for (int k = 0; k < 64; ++k) wA[k] = Wi[k*(3*HH) + n];
        #pragma unroll
        for (int k = 0; k < 64; ++k) wB[k] = Wh[k*(3*HH) + n];
        biv = bi[n];
    } else {
        #pragma unroll
        for (int k = 0; k < 64; ++k) wA[k] = W2[k*HH + lane];
        #pragma unroll
        for (int k = 0; k < 64; ++k) wB[k] = (lane < AA) ? Wl[k*AA + lane]
                                           : (lane == AA ? Wv[k] : 0.f);
        b2v = b2[lane];
        blv = (lane < AA) ? bl[lane] : (lane == AA ? bv[0] : 0.f);
    }
    const float bhnv = (tid < HH) ? bhn[tid] : 0.f;

    if (tid < HH) {
        float v = ic[b*HH + tid];
        ((float*)ic_l)[tid]   = v;
        ((float*)h_l[0])[tid] = v;
    }
    if (tid < OBS) {
        float xv = x[(0*BB + b)*OBS + tid];
        ((float*)&x_l[0][tid>>5])[tid&31] = xv;
    }
    uint8_t m_cur = mask_is_u8 ? m8[b] : (uint8_t)(m32[b] != 0);
    __syncthreads();

    for (int t = 0; t < TT + 2; ++t) {
        const int p = t & 1;
        float xnext = 0.f;
        if (t + 1 < TT && tid < OBS) xnext = x[((t+1)*BB + b)*OBS + tid];
        uint8_t m_next = 0;
        if (t + 1 < TT) {
            const int mi = (t+1)*BB + b;
            m_next = mask_is_u8 ? m8[mi] : (uint8_t)(m32[mi] != 0);
        }
        if (t < TT) {
            const float4* xr = &x_l[p][kc][0];
            float acc = 0.f;
            #pragma unroll
            for (int q = 0; q < 8; ++q) {
                float4 xv = xr[q];
                acc += w1r[4*q+0]*xv.x + w1r[4*q+1]*xv.y
                     + w1r[4*q+2]*xv.z + w1r[4*q+3]*xv.w;
            }
            acc += __shfl_xor(acc, 1);
            acc += __shfl_xor(acc, 2);
            if (kc == 0) ((float*)z_l)[js] = fmaxf(acc + b1v, 0.f);
        }
        if (t < TT && w < 3) {
            const float4* hs = m_cur ? ic_l : h_l[p];
            float acc = 0.f;
            #pragma unroll
            for (int kk = 0; kk < 16; ++kk) {
                float4 hv = hs[kk];
                acc += wB[4*kk+0]*hv.x + wB[4*kk+1]*hv.y
                     + wB[4*kk+2]*hv.z + wB[4*kk+3]*hv.w;
            }
            gh_l[tid] = acc;
        } else if (w == 3 && t >= 1 && t <= TT) {
            const float4* hs = h_l[p];
            float acc = b2v;
            #pragma unroll
            for (int kk = 0; kk < 16; ++kk) {
                float4 hv = hs[kk];
                acc += wA[4*kk+0]*hv.x + wA[4*kk+1]*hv.y
                     + wA[4*kk+2]*hv.z + wA[4*kk+3]*hv.w;
            }
            ((float*)y_l[p])[lane] = fmaxf(acc, 0.f);
        }
        __syncthreads();
        if (t < TT && w < 3) {
            float acc = biv;
            #pragma unroll
            for (int kk = 0; kk < 16; ++kk) {
                float4 zv = z_l[kk];
                acc += wA[4*kk+0]*zv.x + wA[4*kk+1]*zv.y
                     + wA[4*kk+2]*zv.z + wA[4*kk+3]*zv.w;
            }
            gi_l[tid] = acc;
        } else if (w == 3 && t >= 2) {
            const float4* yss = y_l[p ^ 1];
            float acc = blv;
            #pragma unroll
            for (int kk = 0; kk < 16; ++kk) {
                float4 yv = yss[kk];
                acc += wB[4*kk+0]*yv.x + wB[4*kk+1]*yv.y
                     + wB[4*kk+2]*yv.z + wB[4*kk+3]*yv.w;
            }
            if (lane < AA)       out[OFF_L + (size_t)((t-2)*BB + b)*AA + lane] = acc;
            else if (lane == AA) out[OFF_V + (size_t)(t-2)*BB + b] = acc;
        }
        __syncthreads();
        if (t < TT && tid < HH) {
            const int j = tid;
            const float irv = gi_l[j], izv = gi_l[HH+j], inn = gi_l[2*HH+j];
            const float hrv = gh_l[j], hzv = gh_l[HH+j], hnv = gh_l[2*HH+j];
            const float heff = m_cur ? ((const float*)ic_l)[j]
                                     : ((const float*)h_l[p])[j];
            const float r  = sigm(irv + hrv);
            const float u  = sigm(izv + hzv);
            const float nn = tanh_(inn + r*(hnv + bhnv));
            ((float*)h_l[p ^ 1])[j] = u*(heff - nn) + nn;
        }
        if (t + 1 < TT && tid < OBS) {
            ((float*)&x_l[p ^ 1][tid>>5])[tid&31] = xnext;
        }
        m_cur = m_next;
        __syncthreads();
    }
    if (tid < HH) out[(size_t)b*HH + tid] = ((const float*)h_l[TT & 1])[tid];
}

extern "C" void kernel_launch(void* const* d_in, const int* in_sizes, int n_in,
                              void* d_out, int out_size, void* d_ws, size_t ws_size,
                              hipStream_t stream) {
    const float* x    = (const float*)d_in[0];
    const void*  mask = (const void*) d_in[1];
    const float* ic   = (const float*)d_in[2];
    const float* W1   = (const float*)d_in[3];
    const float* b1   = (const float*)d_in[4];
    const float* Wi   = (const float*)d_in[5];
    const float* bi   = (const float*)d_in[6];
    const float* Wh   = (const float*)d_in[7];
    const float* bhn  = (const float*)d_in[8];
    const float* W2   = (const float*)d_in[9];
    const float* b2   = (const float*)d_in[10];
    const float* Wl   = (const float*)d_in[11];
    const float* bl   = (const float*)d_in[12];
    const float* Wv   = (const float*)d_in[13];
    const float* bv   = (const float*)d_in[14];
    float* out = (float*)d_out;

    if (ws_size >= WS_NEED) {
        float* gi = (float*)d_ws;
        float* ys = gi + GI_ELEMS;
        uint32_t* flag = (uint32_t*)(out + OFF_V + RT - 1);
        hipMemsetAsync(flag, 0, sizeof(uint32_t), stream);
        detect_mask<<<64, 256, 0, stream>>>((const uint32_t*)mask, flag);
        stem_gi<<<P1_BLOCKS, 256, 0, stream>>>(x, W1, b1, Wi, bi, gi);
        recur3<<<BB, 192, 0, stream>>>(gi, mask, flag, ic, Wh, bhn, ys, out);
        heads<<<P3_BLOCKS, 256, 0, stream>>>(ys, W2, b2, Wl, bl, Wv, bv, out);
    } else {
        uint32_t* flag = (uint32_t*)d_ws;
        hipMemsetAsync(flag, 0, sizeof(uint32_t), stream);
        detect_mask<<<64, 256, 0, stream>>>((const uint32_t*)mask, flag);
        gru_agent<<<BB, 256, 0, stream>>>(x, mask, flag, ic, W1, b1, Wi, bi, Wh, bhn,
                                          W2, b2, Wl, bl, Wv, bv, out);
    }
}